// Round 2
// baseline (38.478 us; speedup 1.0000x reference)
//
#include <hip/hip_runtime.h>
#include <hip/hip_bf16.h>

// CEKT: y_t = sigmoid([h_t|e_t|x] @ Wp + bp)
//   h_t = (1-g)*prev_h + g*tanh(comb @ Wh + bh),  g = sigmoid(comb @ Wq + bq)
//   comb = [e_t | r_t | prev_h]
// The GAT branch (adj, W_heads, a_heads, W_out, a_out) is dead code w.r.t. y_t.

constexpr int DKc = 128, DHc = 128, DRc = 64, DEc = 128;
constexpr int K1 = DEc + DRc + DHc; // 320
constexpr int K2 = DHc + DEc + DKc; // 384
constexpr int BM = 16;              // rows per block

__device__ __forceinline__ void fma4(float4& acc, const float4 wv, const float s) {
    acc.x = fmaf(wv.x, s, acc.x);
    acc.y = fmaf(wv.y, s, acc.y);
    acc.z = fmaf(wv.z, s, acc.z);
    acc.w = fmaf(wv.w, s, acc.w);
}

__device__ __forceinline__ float sigmoidf_(float z) {
    return 1.0f / (1.0f + expf(-z));
}

__global__ __launch_bounds__(256) void cekt_fused(
    const float* __restrict__ x,
    const float* __restrict__ e_t,
    const float* __restrict__ r_t,
    const float* __restrict__ prev_h,
    const float* __restrict__ Wq, const float* __restrict__ bq,
    const float* __restrict__ Wh, const float* __restrict__ bh,
    const float* __restrict__ Wp, const float* __restrict__ bp,
    float* __restrict__ out)
{
    __shared__ float lds1[BM][K1];   // comb  = [e_t | r_t | prev_h]
    __shared__ float lds2[BM][K2];   // comb2 = [h_t | e_t | x]

    const int t = threadIdx.x;
    const int row0 = blockIdx.x * BM;

    // ---- stage comb (lds1) and the static 2/3 of comb2 (lds2) ----
    for (int i = t; i < BM * DEc; i += 256) {
        const int r = i >> 7, c = i & 127;
        const float v = e_t[(row0 + r) * DEc + c];
        lds1[r][c] = v;
        lds2[r][DHc + c] = v;
    }
    for (int i = t; i < BM * DRc; i += 256) {
        const int r = i >> 6, c = i & 63;
        lds1[r][DEc + c] = r_t[(row0 + r) * DRc + c];
    }
    for (int i = t; i < BM * DHc; i += 256) {
        const int r = i >> 7, c = i & 127;
        lds1[r][DEc + DRc + c] = prev_h[(row0 + r) * DHc + c];
    }
    for (int i = t; i < BM * DKc; i += 256) {
        const int r = i >> 7, c = i & 127;
        lds2[r][DHc + DEc + c] = x[(row0 + r) * DKc + c];
    }
    __syncthreads();

    // thread tile: 2 rows x 4 cols
    const int colq = (t & 31) << 2;  // 0..124 step 4
    const int rg   = t >> 5;         // 0..7
    const int r0   = rg * 2, r1 = r0 + 1;

    // ---- GEMM1: g and cand over K1=320 ----
    float4 ag0 = {0, 0, 0, 0}, ag1 = {0, 0, 0, 0};
    float4 ac0 = {0, 0, 0, 0}, ac1 = {0, 0, 0, 0};
    for (int k = 0; k < K1; k += 4) {
        const float4 cb0 = *(const float4*)&lds1[r0][k];
        const float4 cb1 = *(const float4*)&lds1[r1][k];
#pragma unroll
        for (int kk = 0; kk < 4; ++kk) {
            const float4 wq = *(const float4*)&Wq[(k + kk) * 128 + colq];
            const float4 wh = *(const float4*)&Wh[(k + kk) * 128 + colq];
            const float a0 = (&cb0.x)[kk];
            const float a1 = (&cb1.x)[kk];
            fma4(ag0, wq, a0);
            fma4(ag1, wq, a1);
            fma4(ac0, wh, a0);
            fma4(ac1, wh, a1);
        }
    }

    const float4 bq4 = *(const float4*)&bq[colq];
    const float4 bh4 = *(const float4*)&bh[colq];
    const float4 ph0 = *(const float4*)&lds1[r0][DEc + DRc + colq];
    const float4 ph1 = *(const float4*)&lds1[r1][DEc + DRc + colq];

    float4 h0, h1;
    {
        float g, cd;
        g = sigmoidf_(ag0.x + bq4.x); cd = tanhf(ac0.x + bh4.x); h0.x = (1.0f - g) * ph0.x + g * cd;
        g = sigmoidf_(ag0.y + bq4.y); cd = tanhf(ac0.y + bh4.y); h0.y = (1.0f - g) * ph0.y + g * cd;
        g = sigmoidf_(ag0.z + bq4.z); cd = tanhf(ac0.z + bh4.z); h0.z = (1.0f - g) * ph0.z + g * cd;
        g = sigmoidf_(ag0.w + bq4.w); cd = tanhf(ac0.w + bh4.w); h0.w = (1.0f - g) * ph0.w + g * cd;
        g = sigmoidf_(ag1.x + bq4.x); cd = tanhf(ac1.x + bh4.x); h1.x = (1.0f - g) * ph1.x + g * cd;
        g = sigmoidf_(ag1.y + bq4.y); cd = tanhf(ac1.y + bh4.y); h1.y = (1.0f - g) * ph1.y + g * cd;
        g = sigmoidf_(ag1.z + bq4.z); cd = tanhf(ac1.z + bh4.z); h1.z = (1.0f - g) * ph1.z + g * cd;
        g = sigmoidf_(ag1.w + bq4.w); cd = tanhf(ac1.w + bh4.w); h1.w = (1.0f - g) * ph1.w + g * cd;
    }

    // h_t -> lds2[r][0:128]  (nothing reads lds2[0:128] before the next barrier)
    *(float4*)&lds2[r0][colq] = h0;
    *(float4*)&lds2[r1][colq] = h1;
    __syncthreads();

    // ---- GEMM2: y over K2=384 ----
    float4 ay0 = {0, 0, 0, 0}, ay1 = {0, 0, 0, 0};
    for (int k = 0; k < K2; k += 4) {
        const float4 cb0 = *(const float4*)&lds2[r0][k];
        const float4 cb1 = *(const float4*)&lds2[r1][k];
#pragma unroll
        for (int kk = 0; kk < 4; ++kk) {
            const float4 wp = *(const float4*)&Wp[(k + kk) * 128 + colq];
            const float a0 = (&cb0.x)[kk];
            const float a1 = (&cb1.x)[kk];
            fma4(ay0, wp, a0);
            fma4(ay1, wp, a1);
        }
    }

    const float4 bp4 = *(const float4*)&bp[colq];
    float4 y0, y1;
    y0.x = sigmoidf_(ay0.x + bp4.x); y0.y = sigmoidf_(ay0.y + bp4.y);
    y0.z = sigmoidf_(ay0.z + bp4.z); y0.w = sigmoidf_(ay0.w + bp4.w);
    y1.x = sigmoidf_(ay1.x + bp4.x); y1.y = sigmoidf_(ay1.y + bp4.y);
    y1.z = sigmoidf_(ay1.z + bp4.z); y1.w = sigmoidf_(ay1.w + bp4.w);

    *(float4*)&out[(row0 + r0) * DHc + colq] = y0;
    *(float4*)&out[(row0 + r1) * DHc + colq] = y1;
}

extern "C" void kernel_launch(void* const* d_in, const int* in_sizes, int n_in,
                              void* d_out, int out_size, void* d_ws, size_t ws_size,
                              hipStream_t stream) {
    // setup_inputs order:
    // 0:x 1:adj 2:e_t 3:r_t 4:prev_h 5:W_heads 6:a_heads 7:W_out 8:a_out
    // 9:Wq_w 10:Wq_b 11:Wh_w 12:Wh_b 13:Wp_w 14:Wp_b
    const float* x      = (const float*)d_in[0];
    const float* e_t    = (const float*)d_in[2];
    const float* r_t    = (const float*)d_in[3];
    const float* prev_h = (const float*)d_in[4];
    const float* Wq_w   = (const float*)d_in[9];
    const float* Wq_b   = (const float*)d_in[10];
    const float* Wh_w   = (const float*)d_in[11];
    const float* Wh_b   = (const float*)d_in[12];
    const float* Wp_w   = (const float*)d_in[13];
    const float* Wp_b   = (const float*)d_in[14];
    float* out = (float*)d_out;

    const int N = 4096;
    dim3 grid(N / BM);   // 256 blocks
    dim3 block(256);
    hipLaunchKernelGGL(cekt_fused, grid, block, 0, stream,
                       x, e_t, r_t, prev_h,
                       Wq_w, Wq_b, Wh_w, Wh_b, Wp_w, Wp_b, out);
}